// Round 13
// baseline (2430.007 us; speedup 1.0000x reference)
//
#include <hip/hip_runtime.h>
#include <hip/hip_bf16.h>

#define NNODES 100000
#define DFEAT 128
#define NBKT 8
#define STRIPE 12500            // nodes per dst bucket (100000/8)
#define BUCKET_CAP 416000       // ~400000 expected + big slack
#define CHUNK 4096
#define SUBNODES 64             // nodes per sub-bucket (revert R11's 32)
#define NSUB 196                // ceil(12500/64)
#define SUBCAP 2560             // mean 2041 + 11.5 sigma
#define NSB (NBKT * NSUB)       // 1568 sub-buckets
#define NSLAB 13                // src slabs of 8192 nodes (2MB of Xb each)
#define NBIN (NSLAB * SUBNODES) // 832 bins: slab*64 + node (SLAB-MAJOR)
#define NBINP 1024              // padded for 4-per-thread scan

typedef short bf16x8 __attribute__((ext_vector_type(8)));
typedef float f32x4  __attribute__((ext_vector_type(4)));

__device__ __forceinline__ unsigned short f2bf(float f) {
    unsigned u = __builtin_bit_cast(unsigned, f);
    return (unsigned short)((u + 0x7fffu + ((u >> 16) & 1u)) >> 16);
}

// ---------------------------------------------------------------------------
// Fused prep: [0, n8b)   X fp32 -> bf16
//             [n8b, +128) W1/W2 transpose+cast
//             last block  zero bcur + scur2
// ---------------------------------------------------------------------------
__global__ __launch_bounds__(256)
void prep_all(const float4* __restrict__ X, uint4* __restrict__ Xb, int n8, int n8b,
              const float* __restrict__ w1, const float* __restrict__ w2,
              unsigned short* __restrict__ w1t, unsigned short* __restrict__ w2t,
              int* __restrict__ zbase) {
    const int bid = blockIdx.x;
    const int tid = threadIdx.x;
    if (bid < n8b) {
        int i = bid * 256 + tid;
        if (i >= n8) return;
        float4 a = X[2 * i], b = X[2 * i + 1];
        uint4 o;
        o.x = f2bf(a.x) | ((unsigned)f2bf(a.y) << 16);
        o.y = f2bf(a.z) | ((unsigned)f2bf(a.w) << 16);
        o.z = f2bf(b.x) | ((unsigned)f2bf(b.y) << 16);
        o.w = f2bf(b.z) | ((unsigned)f2bf(b.w) << 16);
        Xb[i] = o;
    } else if (bid < n8b + 128) {
        int i = (bid - n8b) * 256 + tid;          // 0..32767
        const float* w = (i < 16384) ? w1 : w2;
        unsigned short* o = (i < 16384) ? w1t : w2t;
        int j = i & 16383;
        int n = j >> 7, k = j & 127;
        o[n * 128 + k] = f2bf(w[k * 128 + n]);
    } else {
        for (int i = tid; i < 64 + NSB; i += 256) zbase[i] = 0;
    }
}

// ---------------------------------------------------------------------------
// Pass A: partition edges into 8 dst-stripe buckets (validated R5-R11).
// ---------------------------------------------------------------------------
__global__ __launch_bounds__(256)
void partition_edges(const int* __restrict__ dst, const int* __restrict__ src,
                     int* __restrict__ bcur, unsigned* __restrict__ bedges,
                     int nE) {
    __shared__ unsigned sbuf[CHUNK];
    __shared__ int scnt[NBKT];
    __shared__ int sbase[NBKT];
    __shared__ int scur[NBKT];
    __shared__ int gbase[NBKT];

    const int tid = threadIdx.x;
    const long long e0 = (long long)blockIdx.x * CHUNK;
    const int n = (int)min((long long)CHUNK, (long long)nE - e0);
    if (n <= 0) return;

    if (tid < NBKT) scnt[tid] = 0;
    __syncthreads();

    unsigned ent[CHUNK / 256];
    int bkt[CHUNK / 256];
#pragma unroll
    for (int j = 0; j < CHUNK / 256; ++j) {
        int i = tid + j * 256;                    // coalesced
        if (i < n) {
            int d = dst[e0 + i];
            int s = src[e0 + i];
            int b = d / STRIPE;                   // 0..7 (const divisor)
            ent[j] = (unsigned)s | ((unsigned)(d - b * STRIPE) << 17);
            bkt[j] = b;
            atomicAdd(&scnt[b], 1);
        } else bkt[j] = -1;
    }
    __syncthreads();

    if (tid == 0) {
        int run = 0;
        for (int b = 0; b < NBKT; ++b) { sbase[b] = run; scur[b] = run; run += scnt[b]; }
    }
    __syncthreads();

#pragma unroll
    for (int j = 0; j < CHUNK / 256; ++j)
        if (bkt[j] >= 0) {
            int p = atomicAdd(&scur[bkt[j]], 1);
            sbuf[p] = ent[j];
        }
    if (tid < NBKT) gbase[tid] = atomicAdd(&bcur[tid], scnt[tid]);
    __syncthreads();

    for (int i = tid; i < n; i += 256) {
        int b = 0;
        while (b < NBKT - 1 && i >= sbase[b + 1]) ++b;
        bedges[(size_t)b * BUCKET_CAP + gbase[b] + (i - sbase[b])] = sbuf[i];
    }
}

// ---------------------------------------------------------------------------
// Pass B: split each bucket into 196 sub-buckets of 64 nodes (key dst_local>>6).
// R10 config (the R11 391-way split regressed). Wave-parallel segment flush.
// ---------------------------------------------------------------------------
__global__ __launch_bounds__(256)
void partition_sub(const unsigned* __restrict__ bedges, const int* __restrict__ bcur,
                   int* __restrict__ scur2, unsigned* __restrict__ sub_edges) {
    __shared__ unsigned sbuf[CHUNK];
    __shared__ int scnt[NSUB];
    __shared__ int sbase[NSUB + 1];
    __shared__ int scur[NSUB];
    __shared__ int gbase[NSUB];

    const int b   = blockIdx.x & (NBKT - 1);
    const int blk = blockIdx.x >> 3;
    const int sz  = bcur[b];
    const int e0  = blk * CHUNK;
    if (e0 >= sz) return;
    const int n = min(CHUNK, sz - e0);
    const unsigned* p = bedges + (size_t)b * BUCKET_CAP + e0;
    const int tid = threadIdx.x;

    for (int i = tid; i < NSUB; i += 256) scnt[i] = 0;
    __syncthreads();

    unsigned ent[CHUNK / 256];
    int sbk[CHUNK / 256];
#pragma unroll
    for (int j = 0; j < CHUNK / 256; ++j) {
        int i = tid + j * 256;
        if (i < n) {
            unsigned v = p[i];
            int s = (int)(v >> 23);               // dst_local>>6, 0..195
            ent[j] = v;
            sbk[j] = s;
            atomicAdd(&scnt[s], 1);
        } else sbk[j] = -1;
    }
    __syncthreads();

    if (tid == 0) {
        int run = 0;
        for (int s = 0; s < NSUB; ++s) { sbase[s] = run; scur[s] = run; run += scnt[s]; }
        sbase[NSUB] = run;
    }
    __syncthreads();

#pragma unroll
    for (int j = 0; j < CHUNK / 256; ++j)
        if (sbk[j] >= 0) {
            int pos = atomicAdd(&scur[sbk[j]], 1);
            sbuf[pos] = ent[j];
        }
    if (tid < NSUB) gbase[tid] = atomicAdd(&scur2[b * NSUB + tid], scnt[tid]);
    __syncthreads();

    // wave-parallel segment flush: wave w -> segments w, w+4, ...
    const int wave = tid >> 6, lane = tid & 63;
    for (int s = wave; s < NSUB; s += 4) {
        int lo = sbase[s], hi = sbase[s + 1];
        if (lo == hi) continue;
        int g0 = gbase[s];
        unsigned* q = sub_edges + (size_t)(b * NSUB + s) * SUBCAP;
        for (int i = lo + lane; i < hi; i += 64) {
            int o = g0 + (i - lo);
            if (o < SUBCAP) q[o] = sbuf[i];       // statistical overflow guard
        }
    }
}

// ---------------------------------------------------------------------------
// Pass C (R12): slab-major counting sort + EDGE-PARALLEL aggregation into an
// LDS fp32 accumulator tile. Replaces the divergent per-node segment walk
// (R10/R11: wave ran max(seg-len) over 8-16 Poisson(2.45) segments -> ~40%
// slot efficiency). Here: acc[64][129] fp32 in LDS, self-initialized; each
// 16-lane group streams a contiguous chunk of the (slab,node)-sorted edge
// list -- all lanes always active -- and accumulates via ds_add_f32.
// Swizzled acc layout pos=64*(l&1)+(l>>1)+8q: per ds_add instruction a group
// hits 8 banks x 2 lanes (2-way = free, m136); groups are ~4 nodes apart
// (node*129 rotates banks) -> ~2-4-way total. Odd chunk de-banks srt reads.
// Slab-major chunk order preserves the R10 L2-locality win (FETCH 147MB).
// LDS ~51.7KB -> 3 blocks/CU.
// ---------------------------------------------------------------------------
__global__ __launch_bounds__(256, 3)
void sort_aggregate(const unsigned* __restrict__ sub_edges,
                    const int* __restrict__ scur2,
                    const uint4* __restrict__ Xb, uint4* __restrict__ convb) {
    __shared__ float acc[SUBNODES][129];
    __shared__ unsigned srt[SUBCAP];
    __shared__ int cnt[NBINP];         // re-used as cursor after scan
    __shared__ int off[NBIN + 1];
    __shared__ int tmp[256];

    const int b  = blockIdx.x & (NBKT - 1);      // reader XCD == writer XCD
    const int j  = blockIdx.x >> 3;              // 0..195
    const int sb = b * NSUB + j;
    const int tid = threadIdx.x;
    const int sz = min(scur2[sb], SUBCAP);
    const int nodeBase = b * STRIPE + j * SUBNODES;
    const int nLoc = min(SUBNODES, STRIPE - j * SUBNODES);  // 64 (last: 20)
    const unsigned* p = sub_edges + (size_t)sb * SUBCAP;

#pragma unroll
    for (int q = 0; q < 4; ++q) cnt[tid * 4 + q] = 0;
    __syncthreads();
    for (int i = tid; i < sz; i += 256) {
        unsigned v = p[i];
        int key = (int)((v & 0x1FFFFu) >> 13) * SUBNODES + (int)((v >> 17) & 63);
        atomicAdd(&cnt[key], 1);
    }
    __syncthreads();

    // scan 1024 padded bins: 4/thread serial + Hillis-Steele over 256 partials
    int c0 = cnt[tid * 4], c1 = cnt[tid * 4 + 1],
        c2 = cnt[tid * 4 + 2], c3 = cnt[tid * 4 + 3];
    int tot = c0 + c1 + c2 + c3;
    tmp[tid] = tot;
    __syncthreads();
    for (int d = 1; d < 256; d <<= 1) {
        int t = (tid >= d) ? tmp[tid - d] : 0;
        __syncthreads();
        tmp[tid] += t;
        __syncthreads();
    }
    int base = tmp[tid] - tot;                   // exclusive
    int k = tid * 4;
    int b0 = base, b1 = base + c0, b2 = base + c0 + c1, b3 = base + c0 + c1 + c2;
    if (k     <= NBIN) off[k]     = b0;
    if (k + 1 <= NBIN) off[k + 1] = b1;
    if (k + 2 <= NBIN) off[k + 2] = b2;
    if (k + 3 <= NBIN) off[k + 3] = b3;
    __syncthreads();
    cnt[k] = b0; cnt[k + 1] = b1; cnt[k + 2] = b2; cnt[k + 3] = b3;  // cursors
    __syncthreads();

    // scatter FULL entries into (slab, node)-sorted order (LDS only)
    for (int i = tid; i < sz; i += 256) {
        unsigned v = p[i];
        int key = (int)((v & 0x1FFFFu) >> 13) * SUBNODES + (int)((v >> 17) & 63);
        int pos = atomicAdd(&cnt[key], 1);
        srt[pos] = v;
    }

    // self-init acc (swizzled rows; independent of srt, same barrier covers both)
    for (int i = tid; i < SUBNODES * 16; i += 256) {
        int node = i >> 4, l = i & 15;
        uint4 x = make_uint4(0, 0, 0, 0);
        if (node < nLoc) x = Xb[(size_t)(nodeBase + node) * 16 + l];
        int sw = 64 * (l & 1) + (l >> 1);
        acc[node][sw]      = __builtin_bit_cast(float, x.x << 16);
        acc[node][sw + 8]  = __builtin_bit_cast(float, x.x & 0xffff0000u);
        acc[node][sw + 16] = __builtin_bit_cast(float, x.y << 16);
        acc[node][sw + 24] = __builtin_bit_cast(float, x.y & 0xffff0000u);
        acc[node][sw + 32] = __builtin_bit_cast(float, x.z << 16);
        acc[node][sw + 40] = __builtin_bit_cast(float, x.z & 0xffff0000u);
        acc[node][sw + 48] = __builtin_bit_cast(float, x.w << 16);
        acc[node][sw + 56] = __builtin_bit_cast(float, x.w & 0xffff0000u);
    }
    __syncthreads();

    // edge-parallel aggregation: group g streams srt[e0,e1), 16 lanes/edge,
    // ds_add_f32 into acc. No guards, no divergent max-loops.
    {
        const int grp = tid >> 4, lane = tid & 15;
        const int chunk = ((sz + 15) >> 4) | 1;    // odd -> srt reads de-banked
        int e0 = grp * chunk;
        int e1 = min(e0 + chunk, sz);
        const int sw = 64 * (lane & 1) + (lane >> 1);
        for (int e = e0; e < e1; ++e) {
            unsigned v = srt[e];
            int node = (int)((v >> 17) & 63);
            uint4 x = Xb[(size_t)(v & 0x1FFFFu) * 16 + lane];
            atomicAdd(&acc[node][sw],      __builtin_bit_cast(float, x.x << 16));
            atomicAdd(&acc[node][sw + 8],  __builtin_bit_cast(float, x.x & 0xffff0000u));
            atomicAdd(&acc[node][sw + 16], __builtin_bit_cast(float, x.y << 16));
            atomicAdd(&acc[node][sw + 24], __builtin_bit_cast(float, x.y & 0xffff0000u));
            atomicAdd(&acc[node][sw + 32], __builtin_bit_cast(float, x.z << 16));
            atomicAdd(&acc[node][sw + 40], __builtin_bit_cast(float, x.z & 0xffff0000u));
            atomicAdd(&acc[node][sw + 48], __builtin_bit_cast(float, x.w << 16));
            atomicAdd(&acc[node][sw + 56], __builtin_bit_cast(float, x.w & 0xffff0000u));
        }
    }
    __syncthreads();

    // writeout: acc -> bf16 convb (coalesced)
    for (int i = tid; i < nLoc * 16; i += 256) {
        int node = i >> 4, l = i & 15;
        int sw = 64 * (l & 1) + (l >> 1);
        uint4 o;
        o.x = f2bf(acc[node][sw])      | ((unsigned)f2bf(acc[node][sw + 8])  << 16);
        o.y = f2bf(acc[node][sw + 16]) | ((unsigned)f2bf(acc[node][sw + 24]) << 16);
        o.z = f2bf(acc[node][sw + 32]) | ((unsigned)f2bf(acc[node][sw + 40]) << 16);
        o.w = f2bf(acc[node][sw + 48]) | ((unsigned)f2bf(acc[node][sw + 56]) << 16);
        convb[(size_t)(nodeBase + node) * 16 + l] = o;
    }
}

// ---------------------------------------------------------------------------
// Fused MLP via bf16 MFMA (validated R4-R11; H in place in sA, 2 blocks/CU)
// ---------------------------------------------------------------------------
#define TM 128

__global__ __launch_bounds__(256, 2)
void mlp_fused(const unsigned short* __restrict__ convb,
               const unsigned short* __restrict__ w1t, const float* __restrict__ b1,
               const unsigned short* __restrict__ w2t, const float* __restrict__ b2,
               float* __restrict__ out, int N) {
    __shared__ unsigned short sA[TM][136];
    __shared__ unsigned short sW[128][136];

    const int tid  = threadIdx.x;
    const int row0 = blockIdx.x * TM;

    for (int i = tid; i < TM * 16; i += 256) {
        int r = i >> 4, c = i & 15;
        uint4 v = make_uint4(0, 0, 0, 0);
        if (row0 + r < N) v = ((const uint4*)convb)[(size_t)(row0 + r) * 16 + c];
        *(uint4*)&sA[r][c * 8] = v;
    }
    for (int i = tid; i < 128 * 16; i += 256) {
        int r = i >> 4, c = i & 15;
        *(uint4*)&sW[r][c * 8] = ((const uint4*)w1t)[r * 16 + c];
    }
    __syncthreads();

    const int lane = tid & 63;
    const int lrow = lane & 15;
    const int kgrp = lane >> 4;
    const int m0   = (tid >> 6) * 32;

    float bias[8];
#pragma unroll
    for (int nf = 0; nf < 8; ++nf) bias[nf] = b1[nf * 16 + lrow];

    f32x4 acc[2][8] = {};
#pragma unroll
    for (int kk = 0; kk < 128; kk += 32) {
        bf16x8 a0 = *(const bf16x8*)&sA[m0 + lrow][kk + kgrp * 8];
        bf16x8 a1 = *(const bf16x8*)&sA[m0 + 16 + lrow][kk + kgrp * 8];
#pragma unroll
        for (int nf = 0; nf < 8; ++nf) {
            bf16x8 b = *(const bf16x8*)&sW[nf * 16 + lrow][kk + kgrp * 8];
            acc[0][nf] = __builtin_amdgcn_mfma_f32_16x16x32_bf16(a0, b, acc[0][nf], 0, 0, 0);
            acc[1][nf] = __builtin_amdgcn_mfma_f32_16x16x32_bf16(a1, b, acc[1][nf], 0, 0, 0);
        }
    }

    // layer-1 epilogue: relu -> bf16 -> back into sA (own rows only)
#pragma unroll
    for (int mf = 0; mf < 2; ++mf)
#pragma unroll
        for (int nf = 0; nf < 8; ++nf)
#pragma unroll
            for (int r = 0; r < 4; ++r) {
                int row = m0 + mf * 16 + kgrp * 4 + r;
                int col = nf * 16 + lrow;
                float h = fmaxf(acc[mf][nf][r] + bias[nf], 0.f);
                sA[row][col] = f2bf(h);
            }

    __syncthreads();   // all waves past MFMA1 reads of sW; sA(H) complete

    // reload sW <- W2^T
    for (int i = tid; i < 128 * 16; i += 256) {
        int r = i >> 4, c = i & 15;
        *(uint4*)&sW[r][c * 8] = ((const uint4*)w2t)[r * 16 + c];
    }
#pragma unroll
    for (int nf = 0; nf < 8; ++nf) bias[nf] = b2[nf * 16 + lrow];
#pragma unroll
    for (int mf = 0; mf < 2; ++mf)
#pragma unroll
        for (int nf = 0; nf < 8; ++nf) acc[mf][nf] = (f32x4){0.f, 0.f, 0.f, 0.f};
    __syncthreads();

#pragma unroll
    for (int kk = 0; kk < 128; kk += 32) {
        bf16x8 a0 = *(const bf16x8*)&sA[m0 + lrow][kk + kgrp * 8];
        bf16x8 a1 = *(const bf16x8*)&sA[m0 + 16 + lrow][kk + kgrp * 8];
#pragma unroll
        for (int nf = 0; nf < 8; ++nf) {
            bf16x8 b = *(const bf16x8*)&sW[nf * 16 + lrow][kk + kgrp * 8];
            acc[0][nf] = __builtin_amdgcn_mfma_f32_16x16x32_bf16(a0, b, acc[0][nf], 0, 0, 0);
            acc[1][nf] = __builtin_amdgcn_mfma_f32_16x16x32_bf16(a1, b, acc[1][nf], 0, 0, 0);
        }
    }

    // layer-2 epilogue: relu -> fp32 global
#pragma unroll
    for (int mf = 0; mf < 2; ++mf)
#pragma unroll
        for (int nf = 0; nf < 8; ++nf)
#pragma unroll
            for (int r = 0; r < 4; ++r) {
                int row = row0 + m0 + mf * 16 + kgrp * 4 + r;
                int col = nf * 16 + lrow;
                if (row < N)
                    out[(size_t)row * 128 + col] = fmaxf(acc[mf][nf][r] + bias[nf], 0.f);
            }
}

// ---------------------------------------------------------------------------
extern "C" void kernel_launch(void* const* d_in, const int* in_sizes, int n_in,
                              void* d_out, int out_size, void* d_ws, size_t ws_size,
                              hipStream_t stream) {
    const float* X    = (const float*)d_in[0];
    const int*   refA = (const int*)d_in[1];   // dst per edge
    const int*   refB = (const int*)d_in[2];   // src per edge
    const float* w1   = (const float*)d_in[3];
    const float* b1   = (const float*)d_in[4];
    const float* w2   = (const float*)d_in[5];
    const float* b2   = (const float*)d_in[6];
    float* out = (float*)d_out;

    const int nNodes = in_sizes[0] / DFEAT;    // 100000
    const int nE     = in_sizes[1];            // 3200000

    // Workspace layout with liveness-based aliasing:
    //   Xb       : 25.6 MB  (live: prep -> sort_aggregate)
    //   convb    : 25.6 MB  -- ALIASES bedges (13.3 MB). bedges live A->B only;
    //              convb born in pass C. Never simultaneously live.
    //   sub_edges: 16.1 MB  (live: B -> C; disjoint from convb)
    //   w1t/w2t, bcur+scur2 (zeroed inside prep_all)
    char* ws = (char*)d_ws;
    unsigned short* Xb    = (unsigned short*)ws;  ws += (size_t)nNodes * DFEAT * 2;
    unsigned short* convb = (unsigned short*)ws;
    unsigned* bedges      = (unsigned*)convb;     // alias (see above)
    ws += (size_t)nNodes * DFEAT * 2;             // 25.6 MB covers bedges' 13.3 MB
    unsigned* sub_edges = (unsigned*)ws;          ws += (size_t)NSB * SUBCAP * 4;
    unsigned short* w1t = (unsigned short*)ws;    ws += 16384 * 2;
    unsigned short* w2t = (unsigned short*)ws;    ws += 16384 * 2;
    int* bcur  = (int*)ws;                        ws += 64 * 4;
    int* scur2 = (int*)ws;

    // 0) fused prep: x2bf + wprep + zero(bcur,scur2)
    int n8  = nNodes * DFEAT / 8;
    int n8b = (n8 + 255) / 256;
    prep_all<<<n8b + 128 + 1, 256, 0, stream>>>((const float4*)X, (uint4*)Xb, n8, n8b,
                                                w1, w2, w1t, w2t, bcur);

    // 1) two-level edge partition (no global CSR)
    int pBlocks = (nE + CHUNK - 1) / CHUNK;
    partition_edges<<<pBlocks, 256, 0, stream>>>(refA, refB, bcur, bedges, nE);
    partition_sub<<<(BUCKET_CAP / CHUNK + 1) * NBKT, 256, 0, stream>>>(
        bedges, bcur, scur2, sub_edges);

    // 2) slab-major sort + edge-parallel LDS-atomic aggregation
    sort_aggregate<<<NSB, 256, 0, stream>>>(sub_edges, scur2,
                                            (const uint4*)Xb, (uint4*)convb);

    // 3+4) fused MLP via bf16 MFMA
    int mBlocks = (nNodes + TM - 1) / TM;
    mlp_fused<<<mBlocks, 256, 0, stream>>>(convb, w1t, b1, w2t, b2, out, nNodes);
}

// Round 14
// 203.255 us; speedup vs baseline: 11.9554x; 11.9554x over previous
//
#include <hip/hip_runtime.h>
#include <hip/hip_bf16.h>

#define NNODES 100000
#define DFEAT 128
#define NBKT 8
#define STRIPE 12500            // nodes per dst bucket (100000/8)
#define BUCKET_CAP 416000       // ~400000 expected + big slack
#define CHUNK 4096
#define SUBNODES 64             // nodes per sub-bucket
#define NSUB 196                // ceil(12500/64)
#define SUBCAP 2560             // mean 2041 + 11.5 sigma
#define NSB (NBKT * NSUB)       // 1568 sub-buckets
#define NSLAB 13                // src slabs of 8192 nodes (2MB of Xb each)
#define NBIN (NSLAB * SUBNODES) // 832 bins: slab*64 + node (SLAB-MAJOR)
#define NBINP 1024              // padded for 4-per-thread scan

typedef short bf16x8 __attribute__((ext_vector_type(8)));
typedef float f32x4  __attribute__((ext_vector_type(4)));

__device__ __forceinline__ unsigned short f2bf(float f) {
    unsigned u = __builtin_bit_cast(unsigned, f);
    return (unsigned short)((u + 0x7fffu + ((u >> 16) & 1u)) >> 16);
}

// ---------------------------------------------------------------------------
// Tiny prologue: wprep (128 blocks) + zero bcur/scur2 (1 block). Must precede
// part_conv (which reads bcur).
// ---------------------------------------------------------------------------
__global__ __launch_bounds__(256)
void wprep_zero(const float* __restrict__ w1, const float* __restrict__ w2,
                unsigned short* __restrict__ w1t, unsigned short* __restrict__ w2t,
                int* __restrict__ zbase) {
    const int bid = blockIdx.x;
    const int tid = threadIdx.x;
    if (bid < 128) {
        int i = bid * 256 + tid;                  // 0..32767
        const float* w = (i < 16384) ? w1 : w2;
        unsigned short* o = (i < 16384) ? w1t : w2t;
        int j = i & 16383;
        int n = j >> 7, k = j & 127;
        o[n * 128 + k] = f2bf(w[k * 128 + n]);
    } else {
        for (int i = tid; i < 64 + NSB; i += 256) zbase[i] = 0;
    }
}

// ---------------------------------------------------------------------------
// Fused pass: blocks [0, pBlocks) = edge partition into 8 dst-stripe buckets
// (validated R5-R11); blocks [pBlocks, ...) = X fp32 -> bf16 conversion.
// The two phases are independent; fusing overlaps the ~12us conversion with
// the partition's atomic/flush phase instead of serializing it.
// ---------------------------------------------------------------------------
__global__ __launch_bounds__(256)
void part_conv(const int* __restrict__ dst, const int* __restrict__ src,
               int* __restrict__ bcur, unsigned* __restrict__ bedges, int nE,
               int pBlocks, const float4* __restrict__ X, uint4* __restrict__ Xb,
               int n8) {
    const int tid = threadIdx.x;

    if (blockIdx.x >= pBlocks) {                  // --- X conversion blocks ---
        int i = (blockIdx.x - pBlocks) * 256 + tid;
        if (i < n8) {
            float4 a = X[2 * i], b = X[2 * i + 1];
            uint4 o;
            o.x = f2bf(a.x) | ((unsigned)f2bf(a.y) << 16);
            o.y = f2bf(a.z) | ((unsigned)f2bf(a.w) << 16);
            o.z = f2bf(b.x) | ((unsigned)f2bf(b.y) << 16);
            o.w = f2bf(b.z) | ((unsigned)f2bf(b.w) << 16);
            Xb[i] = o;
        }
        return;
    }

    // --- edge partition blocks ---
    __shared__ unsigned sbuf[CHUNK];
    __shared__ int scnt[NBKT];
    __shared__ int sbase[NBKT];
    __shared__ int scur[NBKT];
    __shared__ int gbase[NBKT];

    const long long e0 = (long long)blockIdx.x * CHUNK;
    const int n = (int)min((long long)CHUNK, (long long)nE - e0);
    if (n <= 0) return;

    if (tid < NBKT) scnt[tid] = 0;
    __syncthreads();

    unsigned ent[CHUNK / 256];
    int bkt[CHUNK / 256];
#pragma unroll
    for (int j = 0; j < CHUNK / 256; ++j) {
        int i = tid + j * 256;                    // coalesced
        if (i < n) {
            int d = dst[e0 + i];
            int s = src[e0 + i];
            int b = d / STRIPE;                   // 0..7 (const divisor)
            ent[j] = (unsigned)s | ((unsigned)(d - b * STRIPE) << 17);
            bkt[j] = b;
            atomicAdd(&scnt[b], 1);
        } else bkt[j] = -1;
    }
    __syncthreads();

    if (tid == 0) {
        int run = 0;
        for (int b = 0; b < NBKT; ++b) { sbase[b] = run; scur[b] = run; run += scnt[b]; }
    }
    __syncthreads();

#pragma unroll
    for (int j = 0; j < CHUNK / 256; ++j)
        if (bkt[j] >= 0) {
            int p = atomicAdd(&scur[bkt[j]], 1);
            sbuf[p] = ent[j];
        }
    if (tid < NBKT) gbase[tid] = atomicAdd(&bcur[tid], scnt[tid]);
    __syncthreads();

    for (int i = tid; i < n; i += 256) {
        int b = 0;
        while (b < NBKT - 1 && i >= sbase[b + 1]) ++b;
        bedges[(size_t)b * BUCKET_CAP + gbase[b] + (i - sbase[b])] = sbuf[i];
    }
}

// ---------------------------------------------------------------------------
// Pass B: split each bucket into 196 sub-buckets of 64 nodes (key dst_local>>6).
// Wave-parallel segment flush (R8 fix). Exact R10 version.
// ---------------------------------------------------------------------------
__global__ __launch_bounds__(256)
void partition_sub(const unsigned* __restrict__ bedges, const int* __restrict__ bcur,
                   int* __restrict__ scur2, unsigned* __restrict__ sub_edges) {
    __shared__ unsigned sbuf[CHUNK];
    __shared__ int scnt[NSUB];
    __shared__ int sbase[NSUB + 1];
    __shared__ int scur[NSUB];
    __shared__ int gbase[NSUB];

    const int b   = blockIdx.x & (NBKT - 1);
    const int blk = blockIdx.x >> 3;
    const int sz  = bcur[b];
    const int e0  = blk * CHUNK;
    if (e0 >= sz) return;
    const int n = min(CHUNK, sz - e0);
    const unsigned* p = bedges + (size_t)b * BUCKET_CAP + e0;
    const int tid = threadIdx.x;

    for (int i = tid; i < NSUB; i += 256) scnt[i] = 0;
    __syncthreads();

    unsigned ent[CHUNK / 256];
    int sbk[CHUNK / 256];
#pragma unroll
    for (int j = 0; j < CHUNK / 256; ++j) {
        int i = tid + j * 256;
        if (i < n) {
            unsigned v = p[i];
            int s = (int)(v >> 23);               // dst_local>>6, 0..195
            ent[j] = v;
            sbk[j] = s;
            atomicAdd(&scnt[s], 1);
        } else sbk[j] = -1;
    }
    __syncthreads();

    if (tid == 0) {
        int run = 0;
        for (int s = 0; s < NSUB; ++s) { sbase[s] = run; scur[s] = run; run += scnt[s]; }
        sbase[NSUB] = run;
    }
    __syncthreads();

#pragma unroll
    for (int j = 0; j < CHUNK / 256; ++j)
        if (sbk[j] >= 0) {
            int pos = atomicAdd(&scur[sbk[j]], 1);
            sbuf[pos] = ent[j];
        }
    if (tid < NSUB) gbase[tid] = atomicAdd(&scur2[b * NSUB + tid], scnt[tid]);
    __syncthreads();

    // wave-parallel segment flush: wave w -> segments w, w+4, ...
    const int wave = tid >> 6, lane = tid & 63;
    for (int s = wave; s < NSUB; s += 4) {
        int lo = sbase[s], hi = sbase[s + 1];
        if (lo == hi) continue;
        int g0 = gbase[s];
        unsigned* q = sub_edges + (size_t)(b * NSUB + s) * SUBCAP;
        for (int i = lo + lane; i < hi; i += 64) {
            int o = g0 + (i - lo);
            if (o < SUBCAP) q[o] = sbuf[i];       // statistical overflow guard
        }
    }
}

// ---------------------------------------------------------------------------
// Pass C: slab-major counting sort + quartet-lockstep register aggregation.
// EXACT R10 version (best measured: 115us, FETCH 147MB). R11 (pair/32-node)
// and R12 (LDS-atomic) both regressed — this stage is structural at ~115us:
// 5 structurally different implementations all land 115-133us across
// occupancy 15-62% and FETCH 147-355MB.
// ---------------------------------------------------------------------------
__device__ __forceinline__ void bfadd(float* acc, uint4 v) {
    acc[0] += __builtin_bit_cast(float, v.x << 16);
    acc[1] += __builtin_bit_cast(float, v.x & 0xffff0000u);
    acc[2] += __builtin_bit_cast(float, v.y << 16);
    acc[3] += __builtin_bit_cast(float, v.y & 0xffff0000u);
    acc[4] += __builtin_bit_cast(float, v.z << 16);
    acc[5] += __builtin_bit_cast(float, v.z & 0xffff0000u);
    acc[6] += __builtin_bit_cast(float, v.w << 16);
    acc[7] += __builtin_bit_cast(float, v.w & 0xffff0000u);
}

__device__ __forceinline__ void packout(uint4* convb, int node, int lane,
                                        const float* acc) {
    uint4 o;
    o.x = f2bf(acc[0]) | ((unsigned)f2bf(acc[1]) << 16);
    o.y = f2bf(acc[2]) | ((unsigned)f2bf(acc[3]) << 16);
    o.z = f2bf(acc[4]) | ((unsigned)f2bf(acc[5]) << 16);
    o.w = f2bf(acc[6]) | ((unsigned)f2bf(acc[7]) << 16);
    convb[(size_t)node * 16 + lane] = o;
}

__global__ __launch_bounds__(256, 4)
void sort_aggregate(const unsigned* __restrict__ sub_edges,
                    const int* __restrict__ scur2,
                    const uint4* __restrict__ Xb, uint4* __restrict__ convb) {
    __shared__ unsigned srt[SUBCAP];
    __shared__ int cnt[NBINP];         // re-used as cursor after scan
    __shared__ int off[NBIN + 1];
    __shared__ int tmp[256];

    const int b  = blockIdx.x & (NBKT - 1);      // reader XCD == writer XCD
    const int j  = blockIdx.x >> 3;              // 0..195
    const int sb = b * NSUB + j;
    const int tid = threadIdx.x;
    const int sz = min(scur2[sb], SUBCAP);
    const int nodeBase = b * STRIPE + j * SUBNODES;
    const int nLoc = min(SUBNODES, STRIPE - j * SUBNODES);  // 64 (last: 20)
    const unsigned* p = sub_edges + (size_t)sb * SUBCAP;

#pragma unroll
    for (int q = 0; q < 4; ++q) cnt[tid * 4 + q] = 0;
    __syncthreads();
    for (int i = tid; i < sz; i += 256) {
        unsigned v = p[i];
        int key = (int)((v & 0x1FFFFu) >> 13) * SUBNODES + (int)((v >> 17) & 63);
        atomicAdd(&cnt[key], 1);
    }
    __syncthreads();

    // scan 1024 padded bins: 4/thread serial + Hillis-Steele over 256 partials
    int c0 = cnt[tid * 4], c1 = cnt[tid * 4 + 1],
        c2 = cnt[tid * 4 + 2], c3 = cnt[tid * 4 + 3];
    int tot = c0 + c1 + c2 + c3;
    tmp[tid] = tot;
    __syncthreads();
    for (int d = 1; d < 256; d <<= 1) {
        int t = (tid >= d) ? tmp[tid - d] : 0;
        __syncthreads();
        tmp[tid] += t;
        __syncthreads();
    }
    int base = tmp[tid] - tot;                   // exclusive
    int k = tid * 4;
    int b0 = base, b1 = base + c0, b2 = base + c0 + c1, b3 = base + c0 + c1 + c2;
    if (k     <= NBIN) off[k]     = b0;
    if (k + 1 <= NBIN) off[k + 1] = b1;
    if (k + 2 <= NBIN) off[k + 2] = b2;
    if (k + 3 <= NBIN) off[k + 3] = b3;
    __syncthreads();
    cnt[k] = b0; cnt[k + 1] = b1; cnt[k + 2] = b2; cnt[k + 3] = b3;  // cursors
    __syncthreads();

    // scatter into (slab, node)-sorted order (LDS only)
    for (int i = tid; i < sz; i += 256) {
        unsigned v = p[i];
        unsigned s = v & 0x1FFFFu;
        int key = (int)(s >> 13) * SUBNODES + (int)((v >> 17) & 63);
        int pos = atomicAdd(&cnt[key], 1);
        srt[pos] = s;
    }
    __syncthreads();

    // slab-major aggregation: group g owns nodes g, g+16, g+32, g+48
    const int grp = tid >> 4, lane = tid & 15;
    const int n0 = grp, n1 = grp + 16, n2 = grp + 32, n3 = grp + 48;
    float a0[8], a1[8], a2[8], a3[8];
#pragma unroll
    for (int q = 0; q < 8; ++q) { a0[q] = 0.f; a1[q] = 0.f; a2[q] = 0.f; a3[q] = 0.f; }
    if (n0 < nLoc) bfadd(a0, Xb[(size_t)(nodeBase + n0) * 16 + lane]);  // self
    if (n1 < nLoc) bfadd(a1, Xb[(size_t)(nodeBase + n1) * 16 + lane]);
    if (n2 < nLoc) bfadd(a2, Xb[(size_t)(nodeBase + n2) * 16 + lane]);
    if (n3 < nLoc) bfadd(a3, Xb[(size_t)(nodeBase + n3) * 16 + lane]);

    for (int s = 0; s < NSLAB; ++s) {
        const int kb = s * SUBNODES;
        int e0 = off[kb + n0], x0 = off[kb + n0 + 1];
        int e1 = off[kb + n1], x1 = off[kb + n1 + 1];
        int e2 = off[kb + n2], x2 = off[kb + n2 + 1];
        int e3 = off[kb + n3], x3 = off[kb + n3 + 1];
        int m = max(max(x0 - e0, x1 - e1), max(x2 - e2, x3 - e3));
        for (int t = 0; t < m; ++t) {
            if (e0 + t < x0) bfadd(a0, Xb[(size_t)srt[e0 + t] * 16 + lane]);
            if (e1 + t < x1) bfadd(a1, Xb[(size_t)srt[e1 + t] * 16 + lane]);
            if (e2 + t < x2) bfadd(a2, Xb[(size_t)srt[e2 + t] * 16 + lane]);
            if (e3 + t < x3) bfadd(a3, Xb[(size_t)srt[e3 + t] * 16 + lane]);
        }
    }

    if (n0 < nLoc) packout(convb, nodeBase + n0, lane, a0);
    if (n1 < nLoc) packout(convb, nodeBase + n1, lane, a1);
    if (n2 < nLoc) packout(convb, nodeBase + n2, lane, a2);
    if (n3 < nLoc) packout(convb, nodeBase + n3, lane, a3);
}

// ---------------------------------------------------------------------------
// Fused MLP via bf16 MFMA (validated R4-R11; H in place in sA, 2 blocks/CU)
// ---------------------------------------------------------------------------
#define TM 128

__global__ __launch_bounds__(256, 2)
void mlp_fused(const unsigned short* __restrict__ convb,
               const unsigned short* __restrict__ w1t, const float* __restrict__ b1,
               const unsigned short* __restrict__ w2t, const float* __restrict__ b2,
               float* __restrict__ out, int N) {
    __shared__ unsigned short sA[TM][136];
    __shared__ unsigned short sW[128][136];

    const int tid  = threadIdx.x;
    const int row0 = blockIdx.x * TM;

    for (int i = tid; i < TM * 16; i += 256) {
        int r = i >> 4, c = i & 15;
        uint4 v = make_uint4(0, 0, 0, 0);
        if (row0 + r < N) v = ((const uint4*)convb)[(size_t)(row0 + r) * 16 + c];
        *(uint4*)&sA[r][c * 8] = v;
    }
    for (int i = tid; i < 128 * 16; i += 256) {
        int r = i >> 4, c = i & 15;
        *(uint4*)&sW[r][c * 8] = ((const uint4*)w1t)[r * 16 + c];
    }
    __syncthreads();

    const int lane = tid & 63;
    const int lrow = lane & 15;
    const int kgrp = lane >> 4;
    const int m0   = (tid >> 6) * 32;

    float bias[8];
#pragma unroll
    for (int nf = 0; nf < 8; ++nf) bias[nf] = b1[nf * 16 + lrow];

    f32x4 acc[2][8] = {};
#pragma unroll
    for (int kk = 0; kk < 128; kk += 32) {
        bf16x8 a0 = *(const bf16x8*)&sA[m0 + lrow][kk + kgrp * 8];
        bf16x8 a1 = *(const bf16x8*)&sA[m0 + 16 + lrow][kk + kgrp * 8];
#pragma unroll
        for (int nf = 0; nf < 8; ++nf) {
            bf16x8 b = *(const bf16x8*)&sW[nf * 16 + lrow][kk + kgrp * 8];
            acc[0][nf] = __builtin_amdgcn_mfma_f32_16x16x32_bf16(a0, b, acc[0][nf], 0, 0, 0);
            acc[1][nf] = __builtin_amdgcn_mfma_f32_16x16x32_bf16(a1, b, acc[1][nf], 0, 0, 0);
        }
    }

    // layer-1 epilogue: relu -> bf16 -> back into sA (own rows only)
#pragma unroll
    for (int mf = 0; mf < 2; ++mf)
#pragma unroll
        for (int nf = 0; nf < 8; ++nf)
#pragma unroll
            for (int r = 0; r < 4; ++r) {
                int row = m0 + mf * 16 + kgrp * 4 + r;
                int col = nf * 16 + lrow;
                float h = fmaxf(acc[mf][nf][r] + bias[nf], 0.f);
                sA[row][col] = f2bf(h);
            }

    __syncthreads();   // all waves past MFMA1 reads of sW; sA(H) complete

    // reload sW <- W2^T
    for (int i = tid; i < 128 * 16; i += 256) {
        int r = i >> 4, c = i & 15;
        *(uint4*)&sW[r][c * 8] = ((const uint4*)w2t)[r * 16 + c];
    }
#pragma unroll
    for (int nf = 0; nf < 8; ++nf) bias[nf] = b2[nf * 16 + lrow];
#pragma unroll
    for (int mf = 0; mf < 2; ++mf)
#pragma unroll
        for (int nf = 0; nf < 8; ++nf) acc[mf][nf] = (f32x4){0.f, 0.f, 0.f, 0.f};
    __syncthreads();

#pragma unroll
    for (int kk = 0; kk < 128; kk += 32) {
        bf16x8 a0 = *(const bf16x8*)&sA[m0 + lrow][kk + kgrp * 8];
        bf16x8 a1 = *(const bf16x8*)&sA[m0 + 16 + lrow][kk + kgrp * 8];
#pragma unroll
        for (int nf = 0; nf < 8; ++nf) {
            bf16x8 b = *(const bf16x8*)&sW[nf * 16 + lrow][kk + kgrp * 8];
            acc[0][nf] = __builtin_amdgcn_mfma_f32_16x16x32_bf16(a0, b, acc[0][nf], 0, 0, 0);
            acc[1][nf] = __builtin_amdgcn_mfma_f32_16x16x32_bf16(a1, b, acc[1][nf], 0, 0, 0);
        }
    }

    // layer-2 epilogue: relu -> fp32 global
#pragma unroll
    for (int mf = 0; mf < 2; ++mf)
#pragma unroll
        for (int nf = 0; nf < 8; ++nf)
#pragma unroll
            for (int r = 0; r < 4; ++r) {
                int row = row0 + m0 + mf * 16 + kgrp * 4 + r;
                int col = nf * 16 + lrow;
                if (row < N)
                    out[(size_t)row * 128 + col] = fmaxf(acc[mf][nf][r] + bias[nf], 0.f);
            }
}

// ---------------------------------------------------------------------------
extern "C" void kernel_launch(void* const* d_in, const int* in_sizes, int n_in,
                              void* d_out, int out_size, void* d_ws, size_t ws_size,
                              hipStream_t stream) {
    const float* X    = (const float*)d_in[0];
    const int*   refA = (const int*)d_in[1];   // dst per edge
    const int*   refB = (const int*)d_in[2];   // src per edge
    const float* w1   = (const float*)d_in[3];
    const float* b1   = (const float*)d_in[4];
    const float* w2   = (const float*)d_in[5];
    const float* b2   = (const float*)d_in[6];
    float* out = (float*)d_out;

    const int nNodes = in_sizes[0] / DFEAT;    // 100000
    const int nE     = in_sizes[1];            // 3200000

    // Workspace layout with liveness-based aliasing:
    //   Xb       : 25.6 MB  (live: part_conv -> sort_aggregate)
    //   convb    : 25.6 MB  -- ALIASES bedges (13.3 MB). bedges live A->B only;
    //              convb born in pass C. Never simultaneously live.
    //   sub_edges: 16.1 MB  (live: B -> C; disjoint from convb)
    //   w1t/w2t, bcur+scur2 (zeroed in wprep_zero)
    char* ws = (char*)d_ws;
    unsigned short* Xb    = (unsigned short*)ws;  ws += (size_t)nNodes * DFEAT * 2;
    unsigned short* convb = (unsigned short*)ws;
    unsigned* bedges      = (unsigned*)convb;     // alias (see above)
    ws += (size_t)nNodes * DFEAT * 2;             // 25.6 MB covers bedges' 13.3 MB
    unsigned* sub_edges = (unsigned*)ws;          ws += (size_t)NSB * SUBCAP * 4;
    unsigned short* w1t = (unsigned short*)ws;    ws += 16384 * 2;
    unsigned short* w2t = (unsigned short*)ws;    ws += 16384 * 2;
    int* bcur  = (int*)ws;                        ws += 64 * 4;
    int* scur2 = (int*)ws;

    // 0) prologue: wprep + zero cursors (must precede part_conv)
    wprep_zero<<<129, 256, 0, stream>>>(w1, w2, w1t, w2t, bcur);

    // 1) fused: edge partition (blocks [0,pBlocks)) + X->bf16 (rest)
    int pBlocks = (nE + CHUNK - 1) / CHUNK;
    int n8  = nNodes * DFEAT / 8;
    int n8b = (n8 + 255) / 256;
    part_conv<<<pBlocks + n8b, 256, 0, stream>>>(refA, refB, bcur, bedges, nE,
                                                 pBlocks, (const float4*)X,
                                                 (uint4*)Xb, n8);

    // 2) sub-bucket split
    partition_sub<<<(BUCKET_CAP / CHUNK + 1) * NBKT, 256, 0, stream>>>(
        bedges, bcur, scur2, sub_edges);

    // 3) slab-major sort + quartet register aggregation (R10-exact)
    sort_aggregate<<<NSB, 256, 0, stream>>>(sub_edges, scur2,
                                            (const uint4*)Xb, (uint4*)convb);

    // 4) fused MLP via bf16 MFMA
    int mBlocks = (nNodes + TM - 1) / TM;
    mlp_fused<<<mBlocks, 256, 0, stream>>>(convb, w1t, b1, w2t, b2, out, nNodes);
}